// Round 1
// baseline (1601.294 us; speedup 1.0000x reference)
//
#include <hip/hip_runtime.h>

// ---------------------------------------------------------------------------
// PoetryModel: embed -> x_gates GEMM -> LSTM(128 steps) -> classifier GEMM
//              -> log_softmax over V -> out (B, V, S) f32
// B=64 S=128 V=8000 E=256 H=512 G=4H=2048
// ---------------------------------------------------------------------------

using u16   = unsigned short;
using u16x8 = __attribute__((ext_vector_type(8))) u16;
using bf16x8 = __attribute__((ext_vector_type(8))) __bf16;
using f32x4 = __attribute__((ext_vector_type(4))) float;

#define NB   64        // batch
#define NS   128       // seq len
#define NV   8000      // vocab
#define NVP  8192      // vocab padded to tile
#define NE   256       // embed dim
#define NH   512       // hidden
#define NG   2048      // 4*H
#define NBS  8192      // B*S
#define OUT_BSTRIDE 1024000   // V*S
#define XG_SSTRIDE  131072    // G*B

__device__ inline u16 f2bf(float f) {
    unsigned x = __builtin_bit_cast(unsigned, f);
    unsigned r = (x + 0x7FFFu + ((x >> 16) & 1u)) >> 16;
    return (u16)r;
}

__device__ inline bf16x8 ld_frag(const u16* p) {
    u16x8 v = *(const u16x8*)p;
    return __builtin_bit_cast(bf16x8, v);
}

// ---------------------------------------------------------------- converts
__global__ void cvt_bf16(const float* __restrict__ s, u16* __restrict__ d, int n8) {
    const float4* s4 = (const float4*)s;
    for (int i = blockIdx.x * blockDim.x + threadIdx.x; i < n8;
         i += gridDim.x * blockDim.x) {
        float4 a = s4[2 * i], b = s4[2 * i + 1];
        u16x8 o;
        o[0] = f2bf(a.x); o[1] = f2bf(a.y); o[2] = f2bf(a.z); o[3] = f2bf(a.w);
        o[4] = f2bf(b.x); o[5] = f2bf(b.y); o[6] = f2bf(b.z); o[7] = f2bf(b.w);
        ((u16x8*)d)[i] = o;
    }
}

// ------------------------------------------------- K1: x_gates = x @ W_ih^T
// A = W_ih [2048][256] bf16 (rows g), B = gathered embeddings (rows m=s*64+b)
// C[g][m] + b_ih[g] + b_hh[g] -> xg[s][g][b] f32  (stored in d_out scratch)
__global__ __launch_bounds__(256) void k1_xgates(
    const u16* __restrict__ Wih, const u16* __restrict__ emb,
    const int* __restrict__ toks,
    const float* __restrict__ bih, const float* __restrict__ bhh,
    float* __restrict__ xg)
{
    __shared__ u16x8 Al8[512];   // [128][32] bf16
    __shared__ u16x8 Bl8[512];
    u16* Al = (u16*)Al8;
    u16* Bl = (u16*)Bl8;

    const int t = threadIdx.x;
    const int lane = t & 63, w = t >> 6;
    const int wm = w >> 1, wn = w & 1;
    const int gtile = blockIdx.y * 128, mtile = blockIdx.x * 128;

    const int r0 = t >> 2, r1 = r0 + 64, q = t & 3;
    const int m0 = mtile + r0, m1 = mtile + r1;
    const int tok0 = toks[(m0 & 63) * NS + (m0 >> 6)];
    const int tok1 = toks[(m1 & 63) * NS + (m1 >> 6)];

    f32x4 acc[4][4];
    for (int i = 0; i < 4; ++i)
        for (int j = 0; j < 4; ++j) acc[i][j] = {0.f, 0.f, 0.f, 0.f};

    const int kc8 = (lane >> 4) * 8;
    for (int kk = 0; kk < 8; ++kk) {
        const int k0 = kk * 32;
        *(u16x8*)&Al[t * 8]         = *(const u16x8*)&Wih[(gtile + r0) * NE + k0 + q * 8];
        *(u16x8*)&Al[(t + 256) * 8] = *(const u16x8*)&Wih[(gtile + r1) * NE + k0 + q * 8];
        *(u16x8*)&Bl[t * 8]         = *(const u16x8*)&emb[tok0 * NE + k0 + q * 8];
        *(u16x8*)&Bl[(t + 256) * 8] = *(const u16x8*)&emb[tok1 * NE + k0 + q * 8];
        __syncthreads();
        bf16x8 af[4], bf[4];
        #pragma unroll
        for (int i = 0; i < 4; ++i) {
            af[i] = ld_frag(&Al[(wm * 64 + i * 16 + (lane & 15)) * 32 + kc8]);
            bf[i] = ld_frag(&Bl[(wn * 64 + i * 16 + (lane & 15)) * 32 + kc8]);
        }
        #pragma unroll
        for (int fi = 0; fi < 4; ++fi)
            #pragma unroll
            for (int fj = 0; fj < 4; ++fj)
                acc[fi][fj] = __builtin_amdgcn_mfma_f32_16x16x32_bf16(
                    af[fi], bf[fj], acc[fi][fj], 0, 0, 0);
        __syncthreads();
    }

    #pragma unroll
    for (int fi = 0; fi < 4; ++fi) {
        const int g0 = gtile + wm * 64 + fi * 16 + ((lane >> 4) << 2);
        const float4 v1 = *(const float4*)&bih[g0];
        const float4 v2 = *(const float4*)&bhh[g0];
        float badd[4] = {v1.x + v2.x, v1.y + v2.y, v1.z + v2.z, v1.w + v2.w};
        #pragma unroll
        for (int fj = 0; fj < 4; ++fj) {
            const int m = mtile + wn * 64 + fj * 16 + (lane & 15);
            const int b = m & 63, s = m >> 6;
            float* dst = &xg[s * XG_SSTRIDE + b];
            #pragma unroll
            for (int r = 0; r < 4; ++r)
                dst[(g0 + r) * 64] = acc[fi][fj][r] + badd[r];
        }
    }
}

// --------------------------------------------------------- K2: LSTM (persistent)
// 64 blocks x 512 thr. Block owns 8 hidden units (32 gate rows in registers).
// Per step: gates = h @ Whh^T + xg ; c,h update ; grid barrier.
#define LSTM_NBLK 64

__device__ inline void grid_barrier(unsigned* bar) {
    __syncthreads();
    if (threadIdx.x == 0) {
        unsigned g = __hip_atomic_load(&bar[1], __ATOMIC_RELAXED, __HIP_MEMORY_SCOPE_AGENT);
        unsigned a = __hip_atomic_fetch_add(&bar[0], 1u, __ATOMIC_ACQ_REL, __HIP_MEMORY_SCOPE_AGENT);
        if (a == LSTM_NBLK - 1) {
            __hip_atomic_store(&bar[0], 0u, __ATOMIC_RELAXED, __HIP_MEMORY_SCOPE_AGENT);
            __hip_atomic_store(&bar[1], g + 1u, __ATOMIC_RELEASE, __HIP_MEMORY_SCOPE_AGENT);
        } else {
            while (__hip_atomic_load(&bar[1], __ATOMIC_ACQUIRE, __HIP_MEMORY_SCOPE_AGENT) == g)
                __builtin_amdgcn_s_sleep(2);
        }
    }
    __syncthreads();
}

__global__ __launch_bounds__(512) void k2_lstm(
    const u16* __restrict__ Whh,     // [2048][512] bf16
    const float* __restrict__ xg,    // [S][G][B]
    u16* __restrict__ hbuf,          // [2][64][512] bf16 (zeroed)
    u16* __restrict__ hidden,        // [8192][512] bf16
    unsigned* __restrict__ bar)
{
    __shared__ float gates[64 * 33];

    const int t = threadIdx.x, lane = t & 63, w = t >> 6;
    const int wm = w >> 1, wn = w & 1;          // wm: batch quarter, wn: gate-row half
    const int u0 = blockIdx.x * 8;
    const int kc8 = (lane >> 4) * 8;

    // W_hh fragments resident in registers: 16 x bf16x8 per lane
    const int j  = wn * 16 + (lane & 15);        // 0..31 local gate row
    const int gj = (j >> 3) * 512 + u0 + (j & 7); // global gate row
    bf16x8 bw[16];
    #pragma unroll
    for (int kk = 0; kk < 16; ++kk)
        bw[kk] = ld_frag(&Whh[gj * NH + kk * 32 + kc8]);

    const int bb = t >> 3, uu = t & 7;           // epilogue ownership (batch, unit)
    const int arow = wm * 16 + (lane & 15);      // batch row for A frags
    const int mb = wm * 16 + ((lane >> 4) << 2); // acc batch base
    float creg = 0.f;

    for (int step = 0; step < NS; ++step) {
        const u16* hcur = hbuf + (step & 1) * (NB * NH);
        f32x4 acc0 = {0.f, 0.f, 0.f, 0.f}, acc1 = {0.f, 0.f, 0.f, 0.f};
        #pragma unroll
        for (int kk = 0; kk < 16; kk += 2) {
            bf16x8 a0 = ld_frag(&hcur[arow * NH + kk * 32 + kc8]);
            acc0 = __builtin_amdgcn_mfma_f32_16x16x32_bf16(a0, bw[kk], acc0, 0, 0, 0);
            bf16x8 a1 = ld_frag(&hcur[arow * NH + (kk + 1) * 32 + kc8]);
            acc1 = __builtin_amdgcn_mfma_f32_16x16x32_bf16(a1, bw[kk + 1], acc1, 0, 0, 0);
        }
        const float4 xv = *(const float4*)&xg[step * XG_SSTRIDE + gj * 64 + mb];
        #pragma unroll
        for (int r = 0; r < 4; ++r)
            gates[(mb + r) * 33 + j] = acc0[r] + acc1[r] + (&xv.x)[r];
        __syncthreads();

        {
            float gi = gates[bb * 33 + uu];
            float gf = gates[bb * 33 + 8 + uu];
            float gc = gates[bb * 33 + 16 + uu];
            float go = gates[bb * 33 + 24 + uu];
            float i_ = 1.f / (1.f + __expf(-gi));
            float f_ = 1.f / (1.f + __expf(-gf));
            float e2 = __expf(2.f * gc);
            float g_ = 1.f - 2.f / (e2 + 1.f);
            float o_ = 1.f / (1.f + __expf(-go));
            creg = f_ * creg + i_ * g_;
            float e2c = __expf(2.f * creg);
            float h = o_ * (1.f - 2.f / (e2c + 1.f));
            u16 hb = f2bf(h);
            hbuf[((step & 1) ^ 1) * (NB * NH) + bb * NH + u0 + uu] = hb;
            hidden[(bb * NS + step) * NH + u0 + uu] = hb;
        }
        grid_barrier(bar);
    }
}

// ------------------------------------- K3: logits = hidden @ W_cls^T + b_cls
// A = W_cls padded [8192][512], B = hidden [8192][512], m = b*128+s
// writes out[b][v][s] and atomically accumulates lse[b*128+s] = sum_v exp
__global__ __launch_bounds__(256) void k3_cls(
    const u16* __restrict__ Wc, const u16* __restrict__ hid,
    const float* __restrict__ bcls,
    float* __restrict__ out, float* __restrict__ lse)
{
    __shared__ u16x8 Al8[512];
    __shared__ u16x8 Bl8[512];
    __shared__ float red[2][128];
    u16* Al = (u16*)Al8;
    u16* Bl = (u16*)Bl8;

    const int t = threadIdx.x;
    const int lane = t & 63, w = t >> 6;
    const int wm = w >> 1, wn = w & 1;
    const int vtile = blockIdx.y * 128, mtile = blockIdx.x * 128;

    const int r0 = t >> 2, r1 = r0 + 64, q = t & 3;

    f32x4 acc[4][4];
    for (int i = 0; i < 4; ++i)
        for (int j2 = 0; j2 < 4; ++j2) acc[i][j2] = {0.f, 0.f, 0.f, 0.f};

    const int kc8 = (lane >> 4) * 8;
    for (int kk = 0; kk < 16; ++kk) {
        const int k0 = kk * 32;
        *(u16x8*)&Al[t * 8]         = *(const u16x8*)&Wc[(vtile + r0) * NH + k0 + q * 8];
        *(u16x8*)&Al[(t + 256) * 8] = *(const u16x8*)&Wc[(vtile + r1) * NH + k0 + q * 8];
        *(u16x8*)&Bl[t * 8]         = *(const u16x8*)&hid[(mtile + r0) * NH + k0 + q * 8];
        *(u16x8*)&Bl[(t + 256) * 8] = *(const u16x8*)&hid[(mtile + r1) * NH + k0 + q * 8];
        __syncthreads();
        bf16x8 af[4], bf[4];
        #pragma unroll
        for (int i = 0; i < 4; ++i) {
            af[i] = ld_frag(&Al[(wm * 64 + i * 16 + (lane & 15)) * 32 + kc8]);
            bf[i] = ld_frag(&Bl[(wn * 64 + i * 16 + (lane & 15)) * 32 + kc8]);
        }
        #pragma unroll
        for (int fi = 0; fi < 4; ++fi)
            #pragma unroll
            for (int fj = 0; fj < 4; ++fj)
                acc[fi][fj] = __builtin_amdgcn_mfma_f32_16x16x32_bf16(
                    af[fi], bf[fj], acc[fi][fj], 0, 0, 0);
        __syncthreads();
    }

    float lsum[4] = {0.f, 0.f, 0.f, 0.f};
    #pragma unroll
    for (int fi = 0; fi < 4; ++fi) {
        const int v0 = vtile + wm * 64 + fi * 16 + ((lane >> 4) << 2);
        const bool vok = (v0 < NV);
        float4 bc = {0.f, 0.f, 0.f, 0.f};
        if (vok) bc = *(const float4*)&bcls[v0];
        #pragma unroll
        for (int fj = 0; fj < 4; ++fj) {
            const int m = mtile + wn * 64 + fj * 16 + (lane & 15);
            const int b = m >> 7, s = m & 127;
            if (vok) {
                float* dst = &out[b * OUT_BSTRIDE + v0 * NS + s];
                float e = 0.f;
                #pragma unroll
                for (int r = 0; r < 4; ++r) {
                    float lg = acc[fi][fj][r] + (&bc.x)[r];
                    dst[r * NS] = lg;
                    e += __expf(lg);
                }
                lsum[fj] += e;
            }
        }
    }
    #pragma unroll
    for (int fj = 0; fj < 4; ++fj) {
        lsum[fj] += __shfl_xor(lsum[fj], 16);
        lsum[fj] += __shfl_xor(lsum[fj], 32);
    }
    if (lane < 16) {
        #pragma unroll
        for (int fj = 0; fj < 4; ++fj)
            red[wm][wn * 64 + fj * 16 + lane] = lsum[fj];
    }
    __syncthreads();
    if (t < 128) {
        const int m = mtile + t;
        atomicAdd(&lse[m], red[0][t] + red[1][t]);
    }
}

// ------------------------------------------------------------- K4/K5 epilogue
__global__ void k4_log(const float* __restrict__ lse, float* __restrict__ ll) {
    int i = blockIdx.x * 256 + threadIdx.x;
    if (i < NBS) ll[i] = logf(lse[i]);
}

__global__ void k5_norm(float* __restrict__ out, const float* __restrict__ ll) {
    const int total4 = NB * NV * NS / 4;   // 16,384,000
    float4* o4 = (float4*)out;
    for (int i = blockIdx.x * blockDim.x + threadIdx.x; i < total4;
         i += gridDim.x * blockDim.x) {
        const int i4 = i * 4;
        const int b = i4 / OUT_BSTRIDE;
        const int s = (i4 - b * OUT_BSTRIDE) & 127;
        float4 v = o4[i];
        const float4 l = *(const float4*)&ll[b * NS + s];
        v.x -= l.x; v.y -= l.y; v.z -= l.z; v.w -= l.w;
        o4[i] = v;
    }
}

// ---------------------------------------------------------------------------
extern "C" void kernel_launch(void* const* d_in, const int* in_sizes, int n_in,
                              void* d_out, int out_size, void* d_ws, size_t ws_size,
                              hipStream_t stream) {
    const int*   toks   = (const int*)d_in[0];
    const float* emb_f  = (const float*)d_in[1];
    const float* Wih_f  = (const float*)d_in[2];
    const float* Whh_f  = (const float*)d_in[3];
    const float* bih    = (const float*)d_in[4];
    const float* bhh    = (const float*)d_in[5];
    const float* Wcls_f = (const float*)d_in[6];
    const float* bcls   = (const float*)d_in[7];
    float* out = (float*)d_out;
    char*  ws  = (char*)d_ws;

    // workspace layout (bytes)
    float*    lse    = (float*)(ws + 0);          // 32768
    float*    loglse = (float*)(ws + 32768);      // 32768
    unsigned* bar    = (unsigned*)(ws + 65536);   // 256
    u16*      hbuf   = (u16*)(ws + 65792);        // 131072
    u16*      embb   = (u16*)(ws + 196864);       // 4,096,000
    u16*      wihb   = (u16*)(ws + 4292864);      // 1,048,576
    u16*      whhb   = (u16*)(ws + 5341440);      // 2,097,152
    u16*      wclsb  = (u16*)(ws + 7438592);      // 8,388,608 (padded 8192 rows)
    u16*      hidden = (u16*)(ws + 15827200);     // 8,388,608
    // total: 24,215,808 bytes

    // x_gates f32 [S][G][B] lives in d_out scratch (16.8M floats < 65.5M)
    float* xg = out;

    hipMemsetAsync(ws, 0, 196864, stream);                       // lse + bar + hbuf
    hipMemsetAsync((char*)wclsb + NV * NH * 2, 0, (NVP - NV) * NH * 2, stream);

    cvt_bf16<<<1024, 256, 0, stream>>>(emb_f,  embb,  NV * NE / 8);
    cvt_bf16<<<256,  256, 0, stream>>>(Wih_f,  wihb,  NG * NE / 8);
    cvt_bf16<<<512,  256, 0, stream>>>(Whh_f,  whhb,  NG * NH / 8);
    cvt_bf16<<<1024, 256, 0, stream>>>(Wcls_f, wclsb, NV * NH / 8);

    k1_xgates<<<dim3(64, 16), 256, 0, stream>>>(wihb, embb, toks, bih, bhh, xg);
    k2_lstm<<<LSTM_NBLK, 512, 0, stream>>>(whhb, xg, hbuf, hidden, bar);
    k3_cls<<<dim3(64, 64), 256, 0, stream>>>(wclsb, hidden, bcls, out, lse);
    k4_log<<<32, 256, 0, stream>>>(lse, loglse);
    k5_norm<<<2048, 256, 0, stream>>>(out, loglse);
}

// Round 2
// 1221.191 us; speedup vs baseline: 1.3113x; 1.3113x over previous
//
#include <hip/hip_runtime.h>

// ---------------------------------------------------------------------------
// PoetryModel: embed -> x_gates GEMM -> LSTM(128 steps) -> classifier GEMM
//              -> log_softmax over V -> out (B, V, S) f32
// B=64 S=128 V=8000 E=256 H=512 G=4H=2048
// ---------------------------------------------------------------------------

using u16   = unsigned short;
using u32   = unsigned int;
using u16x8 = __attribute__((ext_vector_type(8))) u16;
using bf16x8 = __attribute__((ext_vector_type(8))) __bf16;
using f32x4 = __attribute__((ext_vector_type(4))) float;

#define NB   64        // batch
#define NS   128       // seq len
#define NV   8000      // vocab
#define NVP  8192      // vocab padded to tile
#define NE   256       // embed dim
#define NH   512       // hidden
#define NG   2048      // 4*H
#define NBS  8192      // B*S
#define OUT_BSTRIDE 1024000   // V*S
#define XG_SSTRIDE  131072    // G*B

__device__ inline u16 f2bf(float f) {
    unsigned x = __builtin_bit_cast(unsigned, f);
    unsigned r = (x + 0x7FFFu + ((x >> 16) & 1u)) >> 16;
    return (u16)r;
}

__device__ inline bf16x8 ld_frag(const u16* p) {
    u16x8 v = *(const u16x8*)p;
    return __builtin_bit_cast(bf16x8, v);
}

// ---------------------------------------------------------------- converts
__global__ void cvt_bf16(const float* __restrict__ s, u16* __restrict__ d, int n8) {
    const float4* s4 = (const float4*)s;
    for (int i = blockIdx.x * blockDim.x + threadIdx.x; i < n8;
         i += gridDim.x * blockDim.x) {
        float4 a = s4[2 * i], b = s4[2 * i + 1];
        u16x8 o;
        o[0] = f2bf(a.x); o[1] = f2bf(a.y); o[2] = f2bf(a.z); o[3] = f2bf(a.w);
        o[4] = f2bf(b.x); o[5] = f2bf(b.y); o[6] = f2bf(b.z); o[7] = f2bf(b.w);
        ((u16x8*)d)[i] = o;
    }
}

// ------------------------------------------------- K1: x_gates = x @ W_ih^T
__global__ __launch_bounds__(256) void k1_xgates(
    const u16* __restrict__ Wih, const u16* __restrict__ emb,
    const int* __restrict__ toks,
    const float* __restrict__ bih, const float* __restrict__ bhh,
    float* __restrict__ xg)
{
    __shared__ u16x8 Al8[512];   // [128][32] bf16
    __shared__ u16x8 Bl8[512];
    u16* Al = (u16*)Al8;
    u16* Bl = (u16*)Bl8;

    const int t = threadIdx.x;
    const int lane = t & 63, w = t >> 6;
    const int wm = w >> 1, wn = w & 1;
    const int gtile = blockIdx.y * 128, mtile = blockIdx.x * 128;

    const int r0 = t >> 2, r1 = r0 + 64, q = t & 3;
    const int m0 = mtile + r0, m1 = mtile + r1;
    const int tok0 = toks[(m0 & 63) * NS + (m0 >> 6)];
    const int tok1 = toks[(m1 & 63) * NS + (m1 >> 6)];

    f32x4 acc[4][4];
    for (int i = 0; i < 4; ++i)
        for (int j = 0; j < 4; ++j) acc[i][j] = {0.f, 0.f, 0.f, 0.f};

    const int kc8 = (lane >> 4) * 8;
    for (int kk = 0; kk < 8; ++kk) {
        const int k0 = kk * 32;
        *(u16x8*)&Al[t * 8]         = *(const u16x8*)&Wih[(gtile + r0) * NE + k0 + q * 8];
        *(u16x8*)&Al[(t + 256) * 8] = *(const u16x8*)&Wih[(gtile + r1) * NE + k0 + q * 8];
        *(u16x8*)&Bl[t * 8]         = *(const u16x8*)&emb[tok0 * NE + k0 + q * 8];
        *(u16x8*)&Bl[(t + 256) * 8] = *(const u16x8*)&emb[tok1 * NE + k0 + q * 8];
        __syncthreads();
        bf16x8 af[4], bf[4];
        #pragma unroll
        for (int i = 0; i < 4; ++i) {
            af[i] = ld_frag(&Al[(wm * 64 + i * 16 + (lane & 15)) * 32 + kc8]);
            bf[i] = ld_frag(&Bl[(wn * 64 + i * 16 + (lane & 15)) * 32 + kc8]);
        }
        #pragma unroll
        for (int fi = 0; fi < 4; ++fi)
            #pragma unroll
            for (int fj = 0; fj < 4; ++fj)
                acc[fi][fj] = __builtin_amdgcn_mfma_f32_16x16x32_bf16(
                    af[fi], bf[fj], acc[fi][fj], 0, 0, 0);
        __syncthreads();
    }

    #pragma unroll
    for (int fi = 0; fi < 4; ++fi) {
        const int g0 = gtile + wm * 64 + fi * 16 + ((lane >> 4) << 2);
        const float4 v1 = *(const float4*)&bih[g0];
        const float4 v2 = *(const float4*)&bhh[g0];
        float badd[4] = {v1.x + v2.x, v1.y + v2.y, v1.z + v2.z, v1.w + v2.w};
        #pragma unroll
        for (int fj = 0; fj < 4; ++fj) {
            const int m = mtile + wn * 64 + fj * 16 + (lane & 15);
            const int b = m & 63, s = m >> 6;
            float* dst = &xg[s * XG_SSTRIDE + b];
            #pragma unroll
            for (int r = 0; r < 4; ++r)
                dst[(g0 + r) * 64] = acc[fi][fj][r] + badd[r];
        }
    }
}

// --------------------------------------------------------- K2: LSTM (persistent)
// 64 blocks x 512 thr. Block owns 8 hidden units (32 gate rows in registers,
// pinned via opaque asm). Sync: per-block flags at LLC, relaxed spin + single
// acquire (one buffer_inv per step) — no wbl2 in the steady state.
#define LSTM_NBLK 64

__global__ __launch_bounds__(512, 2) void k2_lstm(
    const u16* __restrict__ Whh,     // [2048][512] bf16
    const float* __restrict__ xg,    // [S][G][B]
    u16* __restrict__ hbuf,          // [2][64][512] bf16 (zeroed)
    u16* __restrict__ hidden,        // [8192][512] bf16
    u32* __restrict__ flags)         // [64] (zeroed)
{
    __shared__ float gates[64 * 33];
    __shared__ u16 hex[512];

    const int t = threadIdx.x, lane = t & 63, w = t >> 6;
    const int wm = w >> 1, wn = w & 1;          // wm: batch quarter, wn: gate-row half
    const int u0 = blockIdx.x * 8;
    const int kc8 = (lane >> 4) * 8;

    const int j  = wn * 16 + (lane & 15);         // 0..31 local gate row
    const int gj = (j >> 3) * 512 + u0 + (j & 7); // global gate row

    // W_hh fragments resident in registers: 16 x bf16x8 per lane (64 VGPRs),
    // pinned with an opaque asm touch so the compiler cannot rematerialize.
    bf16x8 bw[16];
    #pragma unroll
    for (int kk = 0; kk < 16; ++kk)
        bw[kk] = ld_frag(&Whh[gj * NH + kk * 32 + kc8]);
    #pragma unroll
    for (int kk = 0; kk < 16; ++kk) {
        f32x4 wv = __builtin_bit_cast(f32x4, bw[kk]);
        asm volatile("" : "+v"(wv));
        bw[kk] = __builtin_bit_cast(bf16x8, wv);
    }

    const int bb = t >> 3, uu = t & 7;           // nonlin ownership (batch, unit)
    const int arow = wm * 16 + (lane & 15);      // batch row for A frags
    const int mb = wm * 16 + ((lane >> 4) << 2); // acc batch base
    const int bb2 = t >> 2, uu2 = (t & 3) * 2;   // paired-store ownership
    float creg = 0.f;

    // xv for step 0 prefetched into registers
    float4 xv = *(const float4*)&xg[gj * 64 + mb];

    for (int step = 0; step < NS; ++step) {
        const u16* hcur = hbuf + (step & 1) * (NB * NH);
        f32x4 acc[4];
        #pragma unroll
        for (int i = 0; i < 4; ++i) acc[i] = {0.f, 0.f, 0.f, 0.f};
        #pragma unroll
        for (int kk = 0; kk < 16; ++kk) {
            bf16x8 a0 = ld_frag(&hcur[arow * NH + kk * 32 + kc8]);
            acc[kk & 3] = __builtin_amdgcn_mfma_f32_16x16x32_bf16(
                a0, bw[kk], acc[kk & 3], 0, 0, 0);
        }
        #pragma unroll
        for (int r = 0; r < 4; ++r)
            gates[(mb + r) * 33 + j] =
                acc[0][r] + acc[1][r] + acc[2][r] + acc[3][r] + (&xv.x)[r];
        __syncthreads();

        {
            float gi = gates[bb * 33 + uu];
            float gf = gates[bb * 33 + 8 + uu];
            float gc = gates[bb * 33 + 16 + uu];
            float go = gates[bb * 33 + 24 + uu];
            float i_ = 1.f / (1.f + __expf(-gi));
            float f_ = 1.f / (1.f + __expf(-gf));
            float e2 = __expf(2.f * gc);
            float g_ = 1.f - 2.f / (e2 + 1.f);
            float o_ = 1.f / (1.f + __expf(-go));
            creg = f_ * creg + i_ * g_;
            float e2c = __expf(2.f * creg);
            float h = o_ * (1.f - 2.f / (e2c + 1.f));
            hex[t] = f2bf(h);
        }
        __syncthreads();

        // publish h via coherent u32 stores (bypass L2 dirty state);
        // hidden history via plain stores (flushed at kernel end)
        if (t < 256) {
            u32 pair = ((u32*)hex)[t];
            __hip_atomic_store(
                (u32*)&hbuf[((step & 1) ^ 1) * (NB * NH) + bb2 * NH + u0 + uu2],
                pair, __ATOMIC_RELAXED, __HIP_MEMORY_SCOPE_AGENT);
            *(u32*)&hidden[(bb2 * NS + step) * NH + u0 + uu2] = pair;
        }
        // prefetch next step's xv into registers BEFORE the wait (survives inv)
        if (step + 1 < NS)
            xv = *(const float4*)&xg[(step + 1) * XG_SSTRIDE + gj * 64 + mb];
        __syncthreads();   // drains every thread's stores (vmcnt 0) -> LLC visible

        if (step + 1 < NS) {
            if (t == 0)
                __hip_atomic_store(&flags[blockIdx.x], (u32)(step + 1),
                                   __ATOMIC_RELAXED, __HIP_MEMORY_SCOPE_AGENT);
            if (t < 64) {
                while (__hip_atomic_load(&flags[t], __ATOMIC_RELAXED,
                                         __HIP_MEMORY_SCOPE_AGENT) < (u32)(step + 1))
                    __builtin_amdgcn_s_sleep(1);
                u32 fv = __hip_atomic_load(&flags[t], __ATOMIC_ACQUIRE,
                                           __HIP_MEMORY_SCOPE_AGENT);
                asm volatile("" :: "v"(fv));   // keep the acquire load live
            }
            __syncthreads();
        }
    }
}

// ------------------------------------- K3: logits = hidden @ W_cls^T + b_cls
__global__ __launch_bounds__(256) void k3_cls(
    const u16* __restrict__ Wc, const u16* __restrict__ hid,
    const float* __restrict__ bcls,
    float* __restrict__ out, float* __restrict__ lse)
{
    __shared__ u16x8 Al8[512];
    __shared__ u16x8 Bl8[512];
    __shared__ float red[2][128];
    u16* Al = (u16*)Al8;
    u16* Bl = (u16*)Bl8;

    const int t = threadIdx.x;
    const int lane = t & 63, w = t >> 6;
    const int wm = w >> 1, wn = w & 1;
    const int vtile = blockIdx.y * 128, mtile = blockIdx.x * 128;

    const int r0 = t >> 2, r1 = r0 + 64, q = t & 3;

    f32x4 acc[4][4];
    for (int i = 0; i < 4; ++i)
        for (int j2 = 0; j2 < 4; ++j2) acc[i][j2] = {0.f, 0.f, 0.f, 0.f};

    const int kc8 = (lane >> 4) * 8;
    for (int kk = 0; kk < 16; ++kk) {
        const int k0 = kk * 32;
        *(u16x8*)&Al[t * 8]         = *(const u16x8*)&Wc[(vtile + r0) * NH + k0 + q * 8];
        *(u16x8*)&Al[(t + 256) * 8] = *(const u16x8*)&Wc[(vtile + r1) * NH + k0 + q * 8];
        *(u16x8*)&Bl[t * 8]         = *(const u16x8*)&hid[(mtile + r0) * NH + k0 + q * 8];
        *(u16x8*)&Bl[(t + 256) * 8] = *(const u16x8*)&hid[(mtile + r1) * NH + k0 + q * 8];
        __syncthreads();
        bf16x8 af[4], bf[4];
        #pragma unroll
        for (int i = 0; i < 4; ++i) {
            af[i] = ld_frag(&Al[(wm * 64 + i * 16 + (lane & 15)) * 32 + kc8]);
            bf[i] = ld_frag(&Bl[(wn * 64 + i * 16 + (lane & 15)) * 32 + kc8]);
        }
        #pragma unroll
        for (int fi = 0; fi < 4; ++fi)
            #pragma unroll
            for (int fj = 0; fj < 4; ++fj)
                acc[fi][fj] = __builtin_amdgcn_mfma_f32_16x16x32_bf16(
                    af[fi], bf[fj], acc[fi][fj], 0, 0, 0);
        __syncthreads();
    }

    float lsum[4] = {0.f, 0.f, 0.f, 0.f};
    #pragma unroll
    for (int fi = 0; fi < 4; ++fi) {
        const int v0 = vtile + wm * 64 + fi * 16 + ((lane >> 4) << 2);
        const bool vok = (v0 < NV);
        float4 bc = {0.f, 0.f, 0.f, 0.f};
        if (vok) bc = *(const float4*)&bcls[v0];
        #pragma unroll
        for (int fj = 0; fj < 4; ++fj) {
            const int m = mtile + wn * 64 + fj * 16 + (lane & 15);
            const int b = m >> 7, s = m & 127;
            if (vok) {
                float* dst = &out[b * OUT_BSTRIDE + v0 * NS + s];
                float e = 0.f;
                #pragma unroll
                for (int r = 0; r < 4; ++r) {
                    float lg = acc[fi][fj][r] + (&bc.x)[r];
                    dst[r * NS] = lg;
                    e += __expf(lg);
                }
                lsum[fj] += e;
            }
        }
    }
    #pragma unroll
    for (int fj = 0; fj < 4; ++fj) {
        lsum[fj] += __shfl_xor(lsum[fj], 16);
        lsum[fj] += __shfl_xor(lsum[fj], 32);
    }
    if (lane < 16) {
        #pragma unroll
        for (int fj = 0; fj < 4; ++fj)
            red[wm][wn * 64 + fj * 16 + lane] = lsum[fj];
    }
    __syncthreads();
    if (t < 128) {
        const int m = mtile + t;
        atomicAdd(&lse[m], red[0][t] + red[1][t]);
    }
}

// ------------------------------------------------------------- K4/K5 epilogue
__global__ void k4_log(const float* __restrict__ lse, float* __restrict__ ll) {
    int i = blockIdx.x * 256 + threadIdx.x;
    if (i < NBS) ll[i] = logf(lse[i]);
}

__global__ void k5_norm(float* __restrict__ out, const float* __restrict__ ll) {
    const int total4 = NB * NV * NS / 4;   // 16,384,000
    float4* o4 = (float4*)out;
    for (int i = blockIdx.x * blockDim.x + threadIdx.x; i < total4;
         i += gridDim.x * blockDim.x) {
        const int i4 = i * 4;
        const int b = i4 / OUT_BSTRIDE;
        const int s = (i4 - b * OUT_BSTRIDE) & 127;
        float4 v = o4[i];
        const float4 l = *(const float4*)&ll[b * NS + s];
        v.x -= l.x; v.y -= l.y; v.z -= l.z; v.w -= l.w;
        o4[i] = v;
    }
}

// ---------------------------------------------------------------------------
extern "C" void kernel_launch(void* const* d_in, const int* in_sizes, int n_in,
                              void* d_out, int out_size, void* d_ws, size_t ws_size,
                              hipStream_t stream) {
    const int*   toks   = (const int*)d_in[0];
    const float* emb_f  = (const float*)d_in[1];
    const float* Wih_f  = (const float*)d_in[2];
    const float* Whh_f  = (const float*)d_in[3];
    const float* bih    = (const float*)d_in[4];
    const float* bhh    = (const float*)d_in[5];
    const float* Wcls_f = (const float*)d_in[6];
    const float* bcls   = (const float*)d_in[7];
    float* out = (float*)d_out;
    char*  ws  = (char*)d_ws;

    // workspace layout (bytes)
    float* lse    = (float*)(ws + 0);          // 32768
    float* loglse = (float*)(ws + 32768);      // 32768
    u32*   flags  = (u32*)(ws + 65536);        // 256
    u16*   hbuf   = (u16*)(ws + 65792);        // 131072
    u16*   embb   = (u16*)(ws + 196864);       // 4,096,000
    u16*   wihb   = (u16*)(ws + 4292864);      // 1,048,576
    u16*   whhb   = (u16*)(ws + 5341440);      // 2,097,152
    u16*   wclsb  = (u16*)(ws + 7438592);      // 8,388,608 (padded 8192 rows)
    u16*   hidden = (u16*)(ws + 15827200);     // 8,388,608

    // x_gates f32 [S][G][B] lives in d_out scratch (16.8M floats < 65.5M)
    float* xg = out;

    hipMemsetAsync(ws, 0, 196864, stream);     // lse + loglse + flags + hbuf
    hipMemsetAsync((char*)wclsb + NV * NH * 2, 0, (NVP - NV) * NH * 2, stream);

    cvt_bf16<<<1024, 256, 0, stream>>>(emb_f,  embb,  NV * NE / 8);
    cvt_bf16<<<256,  256, 0, stream>>>(Wih_f,  wihb,  NG * NE / 8);
    cvt_bf16<<<512,  256, 0, stream>>>(Whh_f,  whhb,  NG * NH / 8);
    cvt_bf16<<<1024, 256, 0, stream>>>(Wcls_f, wclsb, NV * NH / 8);

    k1_xgates<<<dim3(64, 16), 256, 0, stream>>>(wihb, embb, toks, bih, bhh, xg);
    k2_lstm<<<LSTM_NBLK, 512, 0, stream>>>(whhb, xg, hbuf, hidden, flags);
    k3_cls<<<dim3(64, 64), 256, 0, stream>>>(wclsb, hidden, bcls, out, lse);
    k4_log<<<32, 256, 0, stream>>>(lse, loglse);
    k5_norm<<<2048, 256, 0, stream>>>(out, loglse);
}